// Round 2
// baseline (556.646 us; speedup 1.0000x reference)
//
#include <hip/hip_runtime.h>
#include <math.h>

#define NT     100000   // total nodes
#define NPT    50000    // nodes per type
#define NPG    50000    // nodes per metapath graph
#define EG     500000   // edges per graph
#define DD     256      // NH*HD
#define TT     20000    // targets per metapath
#define NPB    196      // scan partial blocks per graph (196*256 >= 50000)
#define ACAP   128      // cached scores per (target,head); deg>ACAP recomputes

typedef __attribute__((ext_vector_type(8))) short short8;   // 8 bf16 = 4 VGPRs
typedef __attribute__((ext_vector_type(4))) float f32x4;    // MFMA C/D
typedef unsigned short u16;

#define MFMA16(a, b, c) __builtin_amdgcn_mfma_f32_16x16x32_bf16((a), (b), (c), 0, 0, 0)

// RNE float->bf16 helpers
__device__ inline unsigned pk2(float x, float y) {
    unsigned a = __float_as_uint(x); a = (a + 0x7FFFu + ((a >> 16) & 1u)) >> 16;
    unsigned b = __float_as_uint(y); b = (b + 0x7FFFu + ((b >> 16) & 1u)) >> 16;
    return (a & 0xFFFFu) | (b << 16);
}
__device__ inline u16 pkb(float x) {
    unsigned a = __float_as_uint(x);
    return (u16)((a + 0x7FFFu + ((a >> 16) & 1u)) >> 16);
}
__device__ inline short8 cvt8(float4 a, float4 b) {
    union { int4 i; short8 s; } u;
    u.i = make_int4((int)pk2(a.x, a.y), (int)pk2(a.z, a.w),
                    (int)pk2(b.x, b.y), (int)pk2(b.z, b.w));
    return u.s;
}
__device__ inline float4 up4(unsigned lo, unsigned hi) {
    float4 r;
    r.x = __uint_as_float(lo << 16);
    r.y = __uint_as_float(lo & 0xFFFF0000u);
    r.z = __uint_as_float(hi << 16);
    r.w = __uint_as_float(hi & 0xFFFF0000u);
    return r;
}
__device__ inline float uplo(unsigned w) { return __uint_as_float(w << 16); }
__device__ inline float uphi(unsigned w) { return __uint_as_float(w & 0xFFFF0000u); }
// fast tanh: 1 - 2/(e^{2x}+1) via v_exp_f32 + v_rcp_f32 (rel err ~1e-6)
__device__ inline float ftanh(float x) {
    float e = __expf(2.f * x);
    return 1.f - 2.f * __builtin_amdgcn_rcpf(e + 1.f);
}

// ---------------------------------------------------------------------------
// prep: convert all weights to bf16, transposing to [n][k] where needed.
// ---------------------------------------------------------------------------
__global__ __launch_bounds__(256) void prep_kernel(
    const float* __restrict__ fcW, const float* __restrict__ gatW,
    const float* __restrict__ semW, const float* __restrict__ foW,
    u16* __restrict__ fcWb, u16* __restrict__ gatWb,
    u16* __restrict__ semWb, u16* __restrict__ foWb)
{
    int i = blockIdx.x * 256 + threadIdx.x;
    if (i < 32768) fcWb[i] = pkb(fcW[i]);
    if (i < 65536) {
        int g = i >> 14, rem = i & 16383, n = rem >> 6, k = rem & 63;
        gatWb[i] = pkb(gatW[g * 16384 + k * 256 + n]);
    }
    if (i < 131072) {
        int b = i >> 16, rem = i & 65535, n = rem >> 8, k = rem & 255;
        semWb[i] = pkb(semW[b * 65536 + k * 256 + n]);
    }
    if (i < 32768) {
        int b = i >> 14, rem = i & 16383, n = rem >> 8, k = rem & 255;
        foWb[i] = pkb(foW[b * 16384 + k * 64 + n]);
    }
}

// ---------------------------------------------------------------------------
// fc: tbf[type_idx[ty][r]] = bf16(features_ty @ fc_W[ty]^T + fc_b[ty])
// A loaded flat-coalesced (1 KiB per wave-instr), converted to bf16,
// staged via XOR-swizzled LDS; B staged likewise. LDS = exactly 64 KiB.
// ---------------------------------------------------------------------------
__global__ __launch_bounds__(256) void fc_kernel(
    const float* __restrict__ f0, const float* __restrict__ f1,
    const u16* __restrict__ fcWb, const float* __restrict__ fcb,
    const int* __restrict__ type_idx, u16* __restrict__ tbf)
{
    __shared__ short As[64 * 256];   // swizzled [row][col^((row&15)<<3)]
    __shared__ short Bs[64 * 256];
    int ty = blockIdx.y;
    const float* feat = ty ? f1 : f0;
    const u16* W = fcWb + ty * 64 * 256;
    int tid = threadIdx.x, wv = tid >> 6, l = tid & 63, q = l >> 4, c = l & 15;
    int rbase = blockIdx.x * 64;
    // ---- B: coalesced register load ----
    short8 bv[8];
#pragma unroll
    for (int j = 0; j < 8; ++j)
        bv[j] = *(const short8*)&W[(tid + 256 * j) * 8];
    // ---- A: flat coalesced f32 loads, convert, stage (2 halves) ----
    const float* Abase = feat + (size_t)rbase * 256;
#pragma unroll
    for (int half = 0; half < 2; ++half) {
        float4 va[8];
#pragma unroll
        for (int j = 0; j < 8; ++j) {
            int fi = tid + 256 * (half * 8 + j);       // float4 index in tile
            bool okA = (rbase + (fi >> 6)) < NPT;
            va[j] = okA ? *(const float4*)(Abase + (size_t)fi * 4)
                        : (float4){0.f, 0.f, 0.f, 0.f};
        }
#pragma unroll
        for (int j = 0; j < 8; ++j) {
            int fi = tid + 256 * (half * 8 + j);
            int r = fi >> 6, cs = (fi & 63) * 4;       // 4-short store
            int2 v = make_int2((int)pk2(va[j].x, va[j].y),
                               (int)pk2(va[j].z, va[j].w));
            *(int2*)&As[r * 256 + (cs ^ ((r & 15) << 3))] = v;
        }
    }
    // ---- B -> LDS (swizzled) ----
#pragma unroll
    for (int j = 0; j < 8; ++j) {
        int e = tid + 256 * j, r = e >> 5, cs = (e & 31) * 8;
        *(short8*)&Bs[r * 256 + (cs ^ ((r & 15) << 3))] = bv[j];
    }
    __syncthreads();
    // ---- A fragments from LDS ----
    short8 af[8];
    int arow = wv * 16 + c;                            // arow & 15 == c
#pragma unroll
    for (int s = 0; s < 8; ++s)
        af[s] = *(const short8*)&As[arow * 256 + ((q * 8 + 32 * s) ^ (c << 3))];
    f32x4 acc[4];
#pragma unroll
    for (int i = 0; i < 4; ++i) acc[i] = (f32x4){0.f, 0.f, 0.f, 0.f};
#pragma unroll
    for (int s = 0; s < 8; ++s)
#pragma unroll
        for (int t4 = 0; t4 < 4; ++t4)
            acc[t4] = MFMA16(af[s],
                *(const short8*)&Bs[(t4 * 16 + c) * 256 +
                                    ((q * 8 + 32 * s) ^ (c << 3))], acc[t4]);
    int grl = rbase + wv * 16 + q * 4;
#pragma unroll
    for (int t4 = 0; t4 < 4; ++t4) {
        int col = t4 * 16 + c;
        float bvv = fcb[ty * 64 + col];
#pragma unroll
        for (int reg = 0; reg < 4; ++reg) {
            int gr = grl + reg;
            if (gr < NPT) {
                int dest = type_idx[ty * NPT + gr];
                tbf[(size_t)dest * 64 + col] = pkb(acc[t4][reg] + bvv);
            }
        }
    }
}

// ---------------------------------------------------------------------------
// z = tbf[node_idx] @ gat_W (bf16 out), fused el/er epilogue (fp32).
// Batched over graphs via blockIdx.y (graph g0+y; buffers indexed by y).
// ---------------------------------------------------------------------------
__global__ __launch_bounds__(256) void z_kernel(
    const u16* __restrict__ tbf, const int* __restrict__ nidx4,
    const u16* __restrict__ gatWb4, const float* __restrict__ al4,
    const float* __restrict__ ar4, u16* __restrict__ zb4,
    float* __restrict__ el4, float* __restrict__ er4, int g0)
{
    __shared__ short Bs[256 * 72];
    int gy = blockIdx.y, g = g0 + gy;
    const int* nidx = nidx4 + (size_t)g * NPG;
    const u16* gatWb = gatWb4 + (size_t)g * 16384;
    const float* al = al4 + g * 256;
    const float* ar = ar4 + g * 256;
    u16* zb = zb4 + (size_t)gy * NPG * 256;
    float* el = el4 + (size_t)gy * NPG * 4;
    float* er = er4 + (size_t)gy * NPG * 4;
    int tid = threadIdx.x, wv = tid >> 6, l = tid & 63, q = l >> 4, c = l & 15;
    short8 bv[8];
#pragma unroll
    for (int j = 0; j < 8; ++j)
        bv[j] = *(const short8*)&gatWb[(tid + 256 * j) * 8];
    int rbase = blockIdx.x * 64;
    int row = rbase + wv * 16 + c;
    bool ok = row < NPG;
    short8 af0 = (short8)(short)0, af1 = (short8)(short)0;
    if (ok) {
        int n = nidx[row];
        const u16* Ap = tbf + (size_t)n * 64 + q * 8;
        af0 = *(const short8*)(Ap);
        af1 = *(const short8*)(Ap + 32);
    }
#pragma unroll
    for (int j = 0; j < 8; ++j) {
        int e = tid + 256 * j, r = e >> 3, kc = (e & 7) * 8;
        *(short8*)&Bs[r * 72 + kc] = bv[j];
    }
    __syncthreads();
    f32x4 acc[16];
    const f32x4 zero = (f32x4){0.f, 0.f, 0.f, 0.f};
#pragma unroll
    for (int t16 = 0; t16 < 16; ++t16) {
        const short* Bp = &Bs[(t16 * 16 + c) * 72 + q * 8];
        acc[t16] = MFMA16(af0, *(const short8*)&Bp[0], zero);
        acc[t16] = MFMA16(af1, *(const short8*)&Bp[32], acc[t16]);
    }
    int grl = rbase + wv * 16 + q * 4;
#pragma unroll
    for (int t16 = 0; t16 < 16; ++t16)
#pragma unroll
        for (int reg = 0; reg < 4; ++reg) {
            int gr = grl + reg;
            if (gr < NPG)
                zb[(size_t)gr * 256 + t16 * 16 + c] = pkb(acc[t16][reg]);
        }
    float pl[4][4], pr[4][4];
#pragma unroll
    for (int reg = 0; reg < 4; ++reg)
#pragma unroll
        for (int h = 0; h < 4; ++h) { pl[reg][h] = 0.f; pr[reg][h] = 0.f; }
#pragma unroll
    for (int t16 = 0; t16 < 16; ++t16) {
        int col = t16 * 16 + c, h = t16 >> 2;
        float alv = al[col], arv = ar[col];
#pragma unroll
        for (int reg = 0; reg < 4; ++reg) {
            pl[reg][h] += acc[t16][reg] * alv;
            pr[reg][h] += acc[t16][reg] * arv;
        }
    }
#pragma unroll
    for (int o = 1; o < 16; o <<= 1)
#pragma unroll
        for (int reg = 0; reg < 4; ++reg)
#pragma unroll
            for (int h = 0; h < 4; ++h) {
                pl[reg][h] += __shfl_xor(pl[reg][h], o);
                pr[reg][h] += __shfl_xor(pr[reg][h], o);
            }
    if (c == 0) {
#pragma unroll
        for (int reg = 0; reg < 4; ++reg) {
            int gr = grl + reg;
            if (gr < NPG) {
                float4 vl = {pl[reg][0], pl[reg][1], pl[reg][2], pl[reg][3]};
                float4 vr = {pr[reg][0], pr[reg][1], pr[reg][2], pr[reg][3]};
                *(float4*)&el[gr * 4] = vl;
                *(float4*)&er[gr * 4] = vr;
            }
        }
    }
}

// ---------------------------------------------------------------------------
// CSR build over TARGET nodes only, batched over all 4 graphs.
// ---------------------------------------------------------------------------
__global__ __launch_bounds__(256) void mark_kernel(
    const int* __restrict__ tgt, int* __restrict__ tflag4)
{
    int g = blockIdx.y;
    int i = blockIdx.x * 256 + threadIdx.x;
    if (i < TT) tflag4[g * NPG + tgt[(size_t)g * TT + i]] = 1;
}

__global__ __launch_bounds__(256) void count4_kernel(
    const int* __restrict__ dst, const int* __restrict__ tflag4,
    int* __restrict__ deg4)
{
    int g = blockIdx.y;
    int e = blockIdx.x * 256 + threadIdx.x;
    if (e < EG) {
        int d = dst[(size_t)g * EG + e];
        if (tflag4[g * NPG + d]) atomicAdd(&deg4[g * NPG + d], 1);
    }
}

__device__ inline int block_excl_scan(int v, int tid) {
    __shared__ int wtot[4];
    int lane = tid & 63, w = tid >> 6;
    int x = v;
#pragma unroll
    for (int o = 1; o < 64; o <<= 1) {
        int y = __shfl_up(x, o);
        if (lane >= o) x += y;
    }
    if (lane == 63) wtot[w] = x;
    __syncthreads();
    if (tid == 0) {
        int s = 0;
#pragma unroll
        for (int i = 0; i < 4; ++i) { int t = wtot[i]; wtot[i] = s; s += t; }
    }
    __syncthreads();
    return wtot[w] + x - v;
}

__global__ __launch_bounds__(256) void partial4_kernel(
    const int* __restrict__ deg4, int* __restrict__ part4)
{
    int g = blockIdx.y;
    int i = blockIdx.x * 256 + threadIdx.x;
    int v = (i < NPG) ? deg4[g * NPG + i] : 0;
#pragma unroll
    for (int o = 32; o > 0; o >>= 1) v += __shfl_xor(v, o);
    __shared__ int ws4[4];
    if ((threadIdx.x & 63) == 0) ws4[threadIdx.x >> 6] = v;
    __syncthreads();
    if (threadIdx.x == 0)
        part4[g * NPB + blockIdx.x] = ws4[0] + ws4[1] + ws4[2] + ws4[3];
}

__global__ __launch_bounds__(256) void scanp_kernel(
    const int* __restrict__ part4, int* __restrict__ pref4,
    int* __restrict__ offsets4)
{
    int g = blockIdx.y;
    int t = threadIdx.x;
    int v = (t < NPB) ? part4[g * NPB + t] : 0;
    int e = block_excl_scan(v, t);
    if (t < NPB) pref4[g * NPB + t] = e;
    if (t == 255) offsets4[(size_t)g * (NPG + 1) + NPG] = e + v;  // total
}

__global__ __launch_bounds__(256) void distribute_kernel(
    const int* __restrict__ deg4, const int* __restrict__ pref4,
    int* __restrict__ offsets4, int* __restrict__ cursor4)
{
    int g = blockIdx.y;
    int i = blockIdx.x * 256 + threadIdx.x;
    int v = (i < NPG) ? deg4[g * NPG + i] : 0;
    int e = block_excl_scan(v, threadIdx.x);
    if (i < NPG) {
        int off = pref4[g * NPB + blockIdx.x] + e;
        offsets4[(size_t)g * (NPG + 1) + i] = off;
        cursor4[g * NPG + i] = off;
    }
}

__global__ __launch_bounds__(256) void scatter4_kernel(
    const int* __restrict__ dst, const int* __restrict__ src,
    const int* __restrict__ tflag4, int* __restrict__ cursor4,
    int* __restrict__ perm4)
{
    int g = blockIdx.y;
    int e = blockIdx.x * 256 + threadIdx.x;
    if (e < EG) {
        int d = dst[(size_t)g * EG + e];
        if (tflag4[g * NPG + d]) {
            int pos = atomicAdd(&cursor4[g * NPG + d], 1);
            perm4[(size_t)g * EG + pos] = src[(size_t)g * EG + e];
        }
    }
}

// ---------------------------------------------------------------------------
// Aggregation: one block per target, one wave per head.
// Layout: 4 edge-slots x 16 dim-lanes (4 dims/lane, 8B z-loads).
// Pass 1 computes leaky scores once, caches them in LDS, reduces max.
// Pass 2 reads cached scores (DS broadcast), accumulates 4 dims/lane.
// Cross-slot reduce = 2 butterfly stages x 5 values (vs 3x9 before).
// ---------------------------------------------------------------------------
__global__ __launch_bounds__(256) void agg_kernel(
    const int* __restrict__ tgt4, const int* __restrict__ offsets4,
    const int* __restrict__ perm4, const float* __restrict__ el4,
    const float* __restrict__ er4, const u16* __restrict__ zb4,
    u16* __restrict__ metab4, int g0)
{
    __shared__ float sc[4][ACAP];
    int gy = blockIdx.y, g = g0 + gy;
    const int* tgt = tgt4 + (size_t)g * TT;
    const int* offsets = offsets4 + (size_t)g * (NPG + 1);
    const int* perm = perm4 + (size_t)g * EG;
    const float* el = el4 + (size_t)gy * NPG * 4;
    const float* er = er4 + (size_t)gy * NPG * 4;
    const u16* zb = zb4 + (size_t)gy * NPG * 256;
    u16* metab = metab4 + (size_t)g * TT * 256;
    int t = blockIdx.x;
    int h = threadIdx.x >> 6;
    int lane = threadIdx.x & 63;
    int slot = lane >> 4, dl = lane & 15;
    int dstn = tgt[t];
    int start = offsets[dstn];
    int deg = offsets[dstn + 1] - start;
    float erv = er[dstn * 4 + h];
    // ---- pass 1: scores -> LDS, running max (lanes stride edges) ----
    float mx = -INFINITY;
    for (int i = lane; i < deg; i += 64) {
        float v = el[perm[start + i] * 4 + h] + erv;
        v = fmaxf(v, 0.2f * v);
        if (i < ACAP) sc[h][i] = v;
        mx = fmaxf(mx, v);
    }
#pragma unroll
    for (int o = 32; o > 0; o >>= 1) mx = fmaxf(mx, __shfl_xor(mx, o));
    // ---- pass 2: 4 edge-slots in parallel, 4 dims per lane ----
    float a0 = 0.f, a1 = 0.f, a2 = 0.f, a3 = 0.f, denom = 0.f;
    for (int it = slot; it < deg; it += 4) {
        int s = perm[start + it];
        float v;
        if (it < ACAP) v = sc[h][it];
        else {
            float vv = el[s * 4 + h] + erv;
            v = fmaxf(vv, 0.2f * vv);
        }
        float ex = __expf(v - mx);
        denom += ex;
        uint2 w = *(const uint2*)&zb[(size_t)s * 256 + h * 64 + dl * 4];
        a0 += ex * uplo(w.x); a1 += ex * uphi(w.x);
        a2 += ex * uplo(w.y); a3 += ex * uphi(w.y);
    }
    // ---- cross-slot reduce: slots live in lane bits 4,5 ----
#pragma unroll
    for (int o = 16; o < 64; o <<= 1) {
        denom += __shfl_xor(denom, o);
        a0 += __shfl_xor(a0, o); a1 += __shfl_xor(a1, o);
        a2 += __shfl_xor(a2, o); a3 += __shfl_xor(a3, o);
    }
    if (slot == 0) {
        float inv = __builtin_amdgcn_rcpf(denom + 1e-9f);
        float v0 = a0 * inv, v1 = a1 * inv, v2 = a2 * inv, v3 = a3 * inv;
        v0 = v0 > 0.f ? v0 : (__expf(v0) - 1.f);
        v1 = v1 > 0.f ? v1 : (__expf(v1) - 1.f);
        v2 = v2 > 0.f ? v2 : (__expf(v2) - 1.f);
        v3 = v3 > 0.f ? v3 : (__expf(v3) - 1.f);
        uint2 mw;
        mw.x = pk2(v0, v1); mw.y = pk2(v2, v3);
        *(uint2*)&metab[(size_t)t * 256 + h * 64 + dl * 4] = mw;
    }
}

// ---------------------------------------------------------------------------
// Semantic logits, batched over all 4 graphs (y=g). N-quarters looped
// IN-BLOCK with A-fragments register-resident (A fetched once from HBM).
// wsum[g] += sum_t tanh(meta[g][t]@W[b] + b)@q
// ---------------------------------------------------------------------------
__global__ __launch_bounds__(256) void sem_kernel(
    const u16* __restrict__ metab4, const u16* __restrict__ semWb,
    const float* __restrict__ semb, const float* __restrict__ semq,
    float* __restrict__ wsum4)
{
    __shared__ short Bs[64 * 264];
    __shared__ float bsum;
    int g = blockIdx.y, b = g >> 1;
    const u16* A = metab4 + (size_t)g * TT * 256;
    int tid = threadIdx.x, wv = tid >> 6, l = tid & 63, q = l >> 4, c = l & 15;
    if (tid == 0) bsum = 0.f;
    int rbase = blockIdx.x * 64;
    int row = rbase + wv * 16 + c;
    bool ok = row < TT;
    short8 af[8];
    const u16* Ap = A + (size_t)row * 256 + q * 8;
#pragma unroll
    for (int s = 0; s < 8; ++s)
        af[s] = ok ? *(const short8*)(Ap + 32 * s) : (short8)(short)0;
    float part = 0.f;
    int grl = rbase + wv * 16 + q * 4;
    for (int nq = 0; nq < 4; ++nq) {
        const u16* W = semWb + b * 65536 + nq * 16384;
        short8 bv[8];
#pragma unroll
        for (int j = 0; j < 8; ++j)
            bv[j] = *(const short8*)&W[(tid + 256 * j) * 8];
        __syncthreads();          // previous quarter's Bs reads done
#pragma unroll
        for (int j = 0; j < 8; ++j) {
            int e = tid + 256 * j, r = e >> 5, kc = (e & 31) * 8;
            *(short8*)&Bs[r * 264 + kc] = bv[j];
        }
        __syncthreads();
        f32x4 acc[4];
#pragma unroll
        for (int i = 0; i < 4; ++i) acc[i] = (f32x4){0.f, 0.f, 0.f, 0.f};
#pragma unroll
        for (int s = 0; s < 8; ++s)
#pragma unroll
            for (int t4 = 0; t4 < 4; ++t4)
                acc[t4] = MFMA16(af[s],
                    *(const short8*)&Bs[(t4 * 16 + c) * 264 + q * 8 + 32 * s], acc[t4]);
#pragma unroll
        for (int t4 = 0; t4 < 4; ++t4) {
            int col = nq * 64 + t4 * 16 + c;
            float bb = semb[b * 256 + col], qq = semq[b * 256 + col];
#pragma unroll
            for (int reg = 0; reg < 4; ++reg)
                if (grl + reg < TT) part += ftanh(acc[t4][reg] + bb) * qq;
        }
    }
    for (int o = 32; o > 0; o >>= 1) part += __shfl_xor(part, o);
    if (l == 0) atomicAdd(&bsum, part);
    __syncthreads();
    if (tid == 0) atomicAdd(&wsum4[g], bsum);
}

// ---------------------------------------------------------------------------
// Output, batched over branches (y=b): beta = softmax(wsum[b*2..]/T);
// s = b0*meta0+b1*meta1; out = s@foW + fob
// ---------------------------------------------------------------------------
__global__ __launch_bounds__(256) void out_kernel(
    const u16* __restrict__ metab4, const float* __restrict__ wsum4,
    const u16* __restrict__ foWb, const float* __restrict__ fob,
    float* __restrict__ out)
{
    __shared__ short Bs[64 * 264];
    int b = blockIdx.y;
    int tid = threadIdx.x, wv = tid >> 6, l = tid & 63, q = l >> 4, c = l & 15;
    float w0 = wsum4[b * 2] * (1.f / TT), w1 = wsum4[b * 2 + 1] * (1.f / TT);
    float mxv = fmaxf(w0, w1);
    float e0 = __expf(w0 - mxv), e1 = __expf(w1 - mxv);
    float inv = 1.f / (e0 + e1);
    float b0 = e0 * inv, b1 = e1 * inv;
    const u16* W = foWb + b * 16384;
    short8 bv[8];
#pragma unroll
    for (int j = 0; j < 8; ++j)
        bv[j] = *(const short8*)&W[(tid + 256 * j) * 8];
    int rbase = blockIdx.x * 64;
    int row = rbase + wv * 16 + c;
    bool ok = row < TT;
    const u16* Ap0 = metab4 + (size_t)(b * 2) * TT * 256 + (size_t)row * 256 + q * 8;
    const u16* Ap1 = Ap0 + (size_t)TT * 256;
    short8 af[8];
#pragma unroll
    for (int half = 0; half < 2; ++half) {
        union { short8 s8; uint4 u; } ua[4], uc[4];
#pragma unroll
        for (int s = 0; s < 4; ++s) {
            int ss = half * 4 + s;
            ua[s].s8 = ok ? *(const short8*)(Ap0 + 32 * ss) : (short8)(short)0;
            uc[s].s8 = ok ? *(const short8*)(Ap1 + 32 * ss) : (short8)(short)0;
        }
        if (half == 0) {
#pragma unroll
            for (int j = 0; j < 8; ++j) {
                int e = tid + 256 * j, r = e >> 5, kc = (e & 31) * 8;
                *(short8*)&Bs[r * 264 + kc] = bv[j];
            }
        }
#pragma unroll
        for (int s = 0; s < 4; ++s) {
            float4 a0 = up4(ua[s].u.x, ua[s].u.y), a1 = up4(ua[s].u.z, ua[s].u.w);
            float4 c0 = up4(uc[s].u.x, uc[s].u.y), c1 = up4(uc[s].u.z, uc[s].u.w);
            float4 v0, v1;
            v0.x = b0 * a0.x + b1 * c0.x; v0.y = b0 * a0.y + b1 * c0.y;
            v0.z = b0 * a0.z + b1 * c0.z; v0.w = b0 * a0.w + b1 * c0.w;
            v1.x = b0 * a1.x + b1 * c1.x; v1.y = b0 * a1.y + b1 * c1.y;
            v1.z = b0 * a1.z + b1 * c1.z; v1.w = b0 * a1.w + b1 * c1.w;
            af[half * 4 + s] = cvt8(v0, v1);
        }
    }
    __syncthreads();
    f32x4 acc[4];
#pragma unroll
    for (int i = 0; i < 4; ++i) acc[i] = (f32x4){0.f, 0.f, 0.f, 0.f};
#pragma unroll
    for (int s = 0; s < 8; ++s)
#pragma unroll
        for (int t4 = 0; t4 < 4; ++t4)
            acc[t4] = MFMA16(af[s],
                *(const short8*)&Bs[(t4 * 16 + c) * 264 + q * 8 + 32 * s], acc[t4]);
    int grl = rbase + wv * 16 + q * 4;
#pragma unroll
    for (int t4 = 0; t4 < 4; ++t4) {
        int col = t4 * 16 + c;
        float bvv = fob[b * 64 + col];
#pragma unroll
        for (int reg = 0; reg < 4; ++reg) {
            int gr = grl + reg;
            if (gr < TT)
                out[(size_t)b * TT * 64 + (size_t)gr * 64 + col] = acc[t4][reg] + bvv;
        }
    }
}

// ---------------------------------------------------------------------------
extern "C" void kernel_launch(void* const* d_in, const int* in_sizes, int n_in,
                              void* d_out, int out_size, void* d_ws, size_t ws_size,
                              hipStream_t stream)
{
    const float* f0    = (const float*)d_in[0];
    const float* f1    = (const float*)d_in[1];
    const float* fcW   = (const float*)d_in[2];
    const float* fcb   = (const float*)d_in[3];
    const float* gatW  = (const float*)d_in[4];
    const float* al    = (const float*)d_in[5];
    const float* ar    = (const float*)d_in[6];
    const float* semW  = (const float*)d_in[7];
    const float* semb  = (const float*)d_in[8];
    const float* semq  = (const float*)d_in[9];
    const float* foW   = (const float*)d_in[10];
    const float* fob   = (const float*)d_in[11];
    const int* type_idx = (const int*)d_in[12];
    const int* node_idx = (const int*)d_in[13];
    const int* edge_src = (const int*)d_in[14];
    const int* edge_dst = (const int*)d_in[15];
    const int* tgt_idx  = (const int*)d_in[16];
    float* out = (float*)d_out;

    char* ws = (char*)d_ws;
    size_t off = 0;
    auto alloc = [&](size_t bytes) -> void* {
        void* p = ws + off;
        off = (off + bytes + 255) & ~(size_t)255;
        return p;
    };
    // fixed allocations first
    u16*   tbf         = (u16*)alloc((size_t)NT * 64 * 2);
    u16*   metab4      = (u16*)alloc((size_t)4 * TT * 256 * 2);
    float* wsum4       = (float*)alloc(64);
    u16*   fcWb        = (u16*)alloc(32768 * 2);
    u16*   gatWb       = (u16*)alloc(65536 * 2);
    u16*   semWb       = (u16*)alloc(131072 * 2);
    u16*   foWb        = (u16*)alloc(32768 * 2);
    int*   deg4        = (int*)alloc((size_t)4 * NPG * 4);
    int*   tflag4      = (int*)alloc((size_t)4 * NPG * 4);
    int*   offsets4    = (int*)alloc((size_t)4 * (NPG + 1) * 4);
    int*   cursor4     = (int*)alloc((size_t)4 * NPG * 4);
    int*   perm4       = (int*)alloc((size_t)4 * EG * 4);
    int*   part4       = (int*)alloc((size_t)4 * NPB * 4);
    int*   pref4       = (int*)alloc((size_t)4 * NPB * 4);
    // graph-batched buffers: as many graphs per batch as workspace allows
    const size_t perg = (size_t)NPG * 256 * 2 + 2 * (size_t)NPG * 4 * 4 + 768;
    int GPB = 1;
    {
        size_t rem = (ws_size > off) ? ws_size - off : 0;
        if (rem >= 4 * perg) GPB = 4;
        else if (rem >= 2 * perg) GPB = 2;
    }
    u16*   zb          = (u16*)alloc((size_t)GPB * NPG * 256 * 2);
    float* el          = (float*)alloc((size_t)GPB * NPG * 4 * 4);
    float* er          = (float*)alloc((size_t)GPB * NPG * 4 * 4);

    const int eblocks = (EG + 255) / 256;
    const int tblocks = (TT + 255) / 256;

    prep_kernel<<<512, 256, 0, stream>>>(fcW, gatW, semW, foW,
                                         fcWb, gatWb, semWb, foWb);

    // --- batched target-only CSR build for all 4 graphs ---
    hipMemsetAsync(deg4, 0, (size_t)4 * NPG * 4, stream);
    hipMemsetAsync(tflag4, 0, (size_t)4 * NPG * 4, stream);
    hipMemsetAsync(wsum4, 0, 16, stream);
    mark_kernel<<<dim3(tblocks, 4), 256, 0, stream>>>(tgt_idx, tflag4);
    count4_kernel<<<dim3(eblocks, 4), 256, 0, stream>>>(edge_dst, tflag4, deg4);
    partial4_kernel<<<dim3(NPB, 4), 256, 0, stream>>>(deg4, part4);
    scanp_kernel<<<dim3(1, 4), 256, 0, stream>>>(part4, pref4, offsets4);
    distribute_kernel<<<dim3(NPB, 4), 256, 0, stream>>>(deg4, pref4, offsets4,
                                                        cursor4);
    scatter4_kernel<<<dim3(eblocks, 4), 256, 0, stream>>>(edge_dst, edge_src,
                                                          tflag4, cursor4, perm4);

    fc_kernel<<<dim3(782, 2), 256, 0, stream>>>(f0, f1, fcWb, fcb, type_idx, tbf);
    for (int g0 = 0; g0 < 4; g0 += GPB) {
        z_kernel<<<dim3(782, GPB), 256, 0, stream>>>(
            tbf, node_idx, gatWb, al, ar, zb, el, er, g0);
        agg_kernel<<<dim3(TT, GPB), 256, 0, stream>>>(
            tgt_idx, offsets4, perm4, el, er, zb, metab4, g0);
    }
    sem_kernel<<<dim3(313, 4), 256, 0, stream>>>(metab4, semWb, semb, semq,
                                                 wsum4);
    out_kernel<<<dim3(313, 2), 256, 0, stream>>>(metab4, wsum4, foWb, fob, out);
}

// Round 3
// 464.345 us; speedup vs baseline: 1.1988x; 1.1988x over previous
//
#include <hip/hip_runtime.h>
#include <math.h>

#define NT     100000   // total nodes
#define NPT    50000    // nodes per type
#define NPG    50000    // nodes per metapath graph
#define EG     500000   // edges per graph
#define DD     256      // NH*HD
#define TT     20000    // targets per metapath
#define NPB    196      // scan partial blocks per graph (196*256 >= 50000)

typedef __attribute__((ext_vector_type(8))) short short8;   // 8 bf16 = 4 VGPRs
typedef __attribute__((ext_vector_type(4))) float f32x4;    // MFMA C/D
typedef unsigned short u16;

#define MFMA16(a, b, c) __builtin_amdgcn_mfma_f32_16x16x32_bf16((a), (b), (c), 0, 0, 0)

// RNE float->bf16 helpers
__device__ inline unsigned pk2(float x, float y) {
    unsigned a = __float_as_uint(x); a = (a + 0x7FFFu + ((a >> 16) & 1u)) >> 16;
    unsigned b = __float_as_uint(y); b = (b + 0x7FFFu + ((b >> 16) & 1u)) >> 16;
    return (a & 0xFFFFu) | (b << 16);
}
__device__ inline u16 pkb(float x) {
    unsigned a = __float_as_uint(x);
    return (u16)((a + 0x7FFFu + ((a >> 16) & 1u)) >> 16);
}
__device__ inline short8 cvt8(float4 a, float4 b) {
    union { int4 i; short8 s; } u;
    u.i = make_int4((int)pk2(a.x, a.y), (int)pk2(a.z, a.w),
                    (int)pk2(b.x, b.y), (int)pk2(b.z, b.w));
    return u.s;
}
__device__ inline float4 up4(unsigned lo, unsigned hi) {
    float4 r;
    r.x = __uint_as_float(lo << 16);
    r.y = __uint_as_float(lo & 0xFFFF0000u);
    r.z = __uint_as_float(hi << 16);
    r.w = __uint_as_float(hi & 0xFFFF0000u);
    return r;
}
__device__ inline float uplo(unsigned w) { return __uint_as_float(w << 16); }
__device__ inline float uphi(unsigned w) { return __uint_as_float(w & 0xFFFF0000u); }
// fast tanh: 1 - 2/(e^{2x}+1) via v_exp_f32 + v_rcp_f32 (rel err ~1e-6)
__device__ inline float ftanh(float x) {
    float e = __expf(2.f * x);
    return 1.f - 2.f * __builtin_amdgcn_rcpf(e + 1.f);
}

// ---------------------------------------------------------------------------
// prep: convert all weights to bf16, transposing to [n][k] where needed.
// ---------------------------------------------------------------------------
__global__ __launch_bounds__(256) void prep_kernel(
    const float* __restrict__ fcW, const float* __restrict__ gatW,
    const float* __restrict__ semW, const float* __restrict__ foW,
    u16* __restrict__ fcWb, u16* __restrict__ gatWb,
    u16* __restrict__ semWb, u16* __restrict__ foWb)
{
    int i = blockIdx.x * 256 + threadIdx.x;
    if (i < 32768) fcWb[i] = pkb(fcW[i]);
    if (i < 65536) {
        int g = i >> 14, rem = i & 16383, n = rem >> 6, k = rem & 63;
        gatWb[i] = pkb(gatW[g * 16384 + k * 256 + n]);
    }
    if (i < 131072) {
        int b = i >> 16, rem = i & 65535, n = rem >> 8, k = rem & 255;
        semWb[i] = pkb(semW[b * 65536 + k * 256 + n]);
    }
    if (i < 32768) {
        int b = i >> 14, rem = i & 16383, n = rem >> 8, k = rem & 255;
        foWb[i] = pkb(foW[b * 16384 + k * 64 + n]);
    }
}

// ---------------------------------------------------------------------------
// fc: tbf[type_idx[ty][r]] = bf16(features_ty @ fc_W[ty]^T + fc_b[ty])
// A loaded flat-coalesced (1 KiB per wave-instr), converted to bf16,
// staged via XOR-swizzled LDS; B staged likewise. LDS = exactly 64 KiB.
// ---------------------------------------------------------------------------
__global__ __launch_bounds__(256) void fc_kernel(
    const float* __restrict__ f0, const float* __restrict__ f1,
    const u16* __restrict__ fcWb, const float* __restrict__ fcb,
    const int* __restrict__ type_idx, u16* __restrict__ tbf)
{
    __shared__ short As[64 * 256];   // swizzled [row][col^((row&15)<<3)]
    __shared__ short Bs[64 * 256];
    int ty = blockIdx.y;
    const float* feat = ty ? f1 : f0;
    const u16* W = fcWb + ty * 64 * 256;
    int tid = threadIdx.x, wv = tid >> 6, l = tid & 63, q = l >> 4, c = l & 15;
    int rbase = blockIdx.x * 64;
    // ---- B: coalesced register load ----
    short8 bv[8];
#pragma unroll
    for (int j = 0; j < 8; ++j)
        bv[j] = *(const short8*)&W[(tid + 256 * j) * 8];
    // ---- A: flat coalesced f32 loads, convert, stage (2 halves) ----
    const float* Abase = feat + (size_t)rbase * 256;
#pragma unroll
    for (int half = 0; half < 2; ++half) {
        float4 va[8];
#pragma unroll
        for (int j = 0; j < 8; ++j) {
            int fi = tid + 256 * (half * 8 + j);       // float4 index in tile
            bool okA = (rbase + (fi >> 6)) < NPT;
            va[j] = okA ? *(const float4*)(Abase + (size_t)fi * 4)
                        : (float4){0.f, 0.f, 0.f, 0.f};
        }
#pragma unroll
        for (int j = 0; j < 8; ++j) {
            int fi = tid + 256 * (half * 8 + j);
            int r = fi >> 6, cs = (fi & 63) * 4;       // 4-short store
            int2 v = make_int2((int)pk2(va[j].x, va[j].y),
                               (int)pk2(va[j].z, va[j].w));
            *(int2*)&As[r * 256 + (cs ^ ((r & 15) << 3))] = v;
        }
    }
    // ---- B -> LDS (swizzled) ----
#pragma unroll
    for (int j = 0; j < 8; ++j) {
        int e = tid + 256 * j, r = e >> 5, cs = (e & 31) * 8;
        *(short8*)&Bs[r * 256 + (cs ^ ((r & 15) << 3))] = bv[j];
    }
    __syncthreads();
    // ---- A fragments from LDS ----
    short8 af[8];
    int arow = wv * 16 + c;                            // arow & 15 == c
#pragma unroll
    for (int s = 0; s < 8; ++s)
        af[s] = *(const short8*)&As[arow * 256 + ((q * 8 + 32 * s) ^ (c << 3))];
    f32x4 acc[4];
#pragma unroll
    for (int i = 0; i < 4; ++i) acc[i] = (f32x4){0.f, 0.f, 0.f, 0.f};
#pragma unroll
    for (int s = 0; s < 8; ++s)
#pragma unroll
        for (int t4 = 0; t4 < 4; ++t4)
            acc[t4] = MFMA16(af[s],
                *(const short8*)&Bs[(t4 * 16 + c) * 256 +
                                    ((q * 8 + 32 * s) ^ (c << 3))], acc[t4]);
    int grl = rbase + wv * 16 + q * 4;
#pragma unroll
    for (int t4 = 0; t4 < 4; ++t4) {
        int col = t4 * 16 + c;
        float bvv = fcb[ty * 64 + col];
#pragma unroll
        for (int reg = 0; reg < 4; ++reg) {
            int gr = grl + reg;
            if (gr < NPT) {
                int dest = type_idx[ty * NPT + gr];
                tbf[(size_t)dest * 64 + col] = pkb(acc[t4][reg] + bvv);
            }
        }
    }
}

// ---------------------------------------------------------------------------
// z = tbf[node_idx] @ gat_W (bf16 out), fused el/er epilogue (fp32).
// Batched over graphs via blockIdx.y (graph g0+y; buffers indexed by y).
// ---------------------------------------------------------------------------
__global__ __launch_bounds__(256) void z_kernel(
    const u16* __restrict__ tbf, const int* __restrict__ nidx4,
    const u16* __restrict__ gatWb4, const float* __restrict__ al4,
    const float* __restrict__ ar4, u16* __restrict__ zb4,
    float* __restrict__ el4, float* __restrict__ er4, int g0)
{
    __shared__ short Bs[256 * 72];
    int gy = blockIdx.y, g = g0 + gy;
    const int* nidx = nidx4 + (size_t)g * NPG;
    const u16* gatWb = gatWb4 + (size_t)g * 16384;
    const float* al = al4 + g * 256;
    const float* ar = ar4 + g * 256;
    u16* zb = zb4 + (size_t)gy * NPG * 256;
    float* el = el4 + (size_t)gy * NPG * 4;
    float* er = er4 + (size_t)gy * NPG * 4;
    int tid = threadIdx.x, wv = tid >> 6, l = tid & 63, q = l >> 4, c = l & 15;
    short8 bv[8];
#pragma unroll
    for (int j = 0; j < 8; ++j)
        bv[j] = *(const short8*)&gatWb[(tid + 256 * j) * 8];
    int rbase = blockIdx.x * 64;
    int row = rbase + wv * 16 + c;
    bool ok = row < NPG;
    short8 af0 = (short8)(short)0, af1 = (short8)(short)0;
    if (ok) {
        int n = nidx[row];
        const u16* Ap = tbf + (size_t)n * 64 + q * 8;
        af0 = *(const short8*)(Ap);
        af1 = *(const short8*)(Ap + 32);
    }
#pragma unroll
    for (int j = 0; j < 8; ++j) {
        int e = tid + 256 * j, r = e >> 3, kc = (e & 7) * 8;
        *(short8*)&Bs[r * 72 + kc] = bv[j];
    }
    __syncthreads();
    f32x4 acc[16];
    const f32x4 zero = (f32x4){0.f, 0.f, 0.f, 0.f};
#pragma unroll
    for (int t16 = 0; t16 < 16; ++t16) {
        const short* Bp = &Bs[(t16 * 16 + c) * 72 + q * 8];
        acc[t16] = MFMA16(af0, *(const short8*)&Bp[0], zero);
        acc[t16] = MFMA16(af1, *(const short8*)&Bp[32], acc[t16]);
    }
    int grl = rbase + wv * 16 + q * 4;
#pragma unroll
    for (int t16 = 0; t16 < 16; ++t16)
#pragma unroll
        for (int reg = 0; reg < 4; ++reg) {
            int gr = grl + reg;
            if (gr < NPG)
                zb[(size_t)gr * 256 + t16 * 16 + c] = pkb(acc[t16][reg]);
        }
    float pl[4][4], pr[4][4];
#pragma unroll
    for (int reg = 0; reg < 4; ++reg)
#pragma unroll
        for (int h = 0; h < 4; ++h) { pl[reg][h] = 0.f; pr[reg][h] = 0.f; }
#pragma unroll
    for (int t16 = 0; t16 < 16; ++t16) {
        int col = t16 * 16 + c, h = t16 >> 2;
        float alv = al[col], arv = ar[col];
#pragma unroll
        for (int reg = 0; reg < 4; ++reg) {
            pl[reg][h] += acc[t16][reg] * alv;
            pr[reg][h] += acc[t16][reg] * arv;
        }
    }
#pragma unroll
    for (int o = 1; o < 16; o <<= 1)
#pragma unroll
        for (int reg = 0; reg < 4; ++reg)
#pragma unroll
            for (int h = 0; h < 4; ++h) {
                pl[reg][h] += __shfl_xor(pl[reg][h], o);
                pr[reg][h] += __shfl_xor(pr[reg][h], o);
            }
    if (c == 0) {
#pragma unroll
        for (int reg = 0; reg < 4; ++reg) {
            int gr = grl + reg;
            if (gr < NPG) {
                float4 vl = {pl[reg][0], pl[reg][1], pl[reg][2], pl[reg][3]};
                float4 vr = {pr[reg][0], pr[reg][1], pr[reg][2], pr[reg][3]};
                *(float4*)&el[gr * 4] = vl;
                *(float4*)&er[gr * 4] = vr;
            }
        }
    }
}

// ---------------------------------------------------------------------------
// CSR build over TARGET nodes only, batched over all 4 graphs.
// ---------------------------------------------------------------------------
__global__ __launch_bounds__(256) void mark_kernel(
    const int* __restrict__ tgt, int* __restrict__ tflag4)
{
    int g = blockIdx.y;
    int i = blockIdx.x * 256 + threadIdx.x;
    if (i < TT) tflag4[g * NPG + tgt[(size_t)g * TT + i]] = 1;
}

__global__ __launch_bounds__(256) void count4_kernel(
    const int* __restrict__ dst, const int* __restrict__ tflag4,
    int* __restrict__ deg4)
{
    int g = blockIdx.y;
    int e = blockIdx.x * 256 + threadIdx.x;
    if (e < EG) {
        int d = dst[(size_t)g * EG + e];
        if (tflag4[g * NPG + d]) atomicAdd(&deg4[g * NPG + d], 1);
    }
}

__device__ inline int block_excl_scan(int v, int tid) {
    __shared__ int wtot[4];
    int lane = tid & 63, w = tid >> 6;
    int x = v;
#pragma unroll
    for (int o = 1; o < 64; o <<= 1) {
        int y = __shfl_up(x, o);
        if (lane >= o) x += y;
    }
    if (lane == 63) wtot[w] = x;
    __syncthreads();
    if (tid == 0) {
        int s = 0;
#pragma unroll
        for (int i = 0; i < 4; ++i) { int t = wtot[i]; wtot[i] = s; s += t; }
    }
    __syncthreads();
    return wtot[w] + x - v;
}

__global__ __launch_bounds__(256) void partial4_kernel(
    const int* __restrict__ deg4, int* __restrict__ part4)
{
    int g = blockIdx.y;
    int i = blockIdx.x * 256 + threadIdx.x;
    int v = (i < NPG) ? deg4[g * NPG + i] : 0;
#pragma unroll
    for (int o = 32; o > 0; o >>= 1) v += __shfl_xor(v, o);
    __shared__ int ws4[4];
    if ((threadIdx.x & 63) == 0) ws4[threadIdx.x >> 6] = v;
    __syncthreads();
    if (threadIdx.x == 0)
        part4[g * NPB + blockIdx.x] = ws4[0] + ws4[1] + ws4[2] + ws4[3];
}

__global__ __launch_bounds__(256) void scanp_kernel(
    const int* __restrict__ part4, int* __restrict__ pref4,
    int* __restrict__ offsets4)
{
    int g = blockIdx.y;
    int t = threadIdx.x;
    int v = (t < NPB) ? part4[g * NPB + t] : 0;
    int e = block_excl_scan(v, t);
    if (t < NPB) pref4[g * NPB + t] = e;
    if (t == 255) offsets4[(size_t)g * (NPG + 1) + NPG] = e + v;  // total
}

__global__ __launch_bounds__(256) void distribute_kernel(
    const int* __restrict__ deg4, const int* __restrict__ pref4,
    int* __restrict__ offsets4, int* __restrict__ cursor4)
{
    int g = blockIdx.y;
    int i = blockIdx.x * 256 + threadIdx.x;
    int v = (i < NPG) ? deg4[g * NPG + i] : 0;
    int e = block_excl_scan(v, threadIdx.x);
    if (i < NPG) {
        int off = pref4[g * NPB + blockIdx.x] + e;
        offsets4[(size_t)g * (NPG + 1) + i] = off;
        cursor4[g * NPG + i] = off;
    }
}

__global__ __launch_bounds__(256) void scatter4_kernel(
    const int* __restrict__ dst, const int* __restrict__ src,
    const int* __restrict__ tflag4, int* __restrict__ cursor4,
    int* __restrict__ perm4)
{
    int g = blockIdx.y;
    int e = blockIdx.x * 256 + threadIdx.x;
    if (e < EG) {
        int d = dst[(size_t)g * EG + e];
        if (tflag4[g * NPG + d]) {
            int pos = atomicAdd(&cursor4[g * NPG + d], 1);
            perm4[(size_t)g * EG + pos] = src[(size_t)g * EG + e];
        }
    }
}

// ---------------------------------------------------------------------------
// Aggregation: ONE WAVE per target covering ALL 4 heads.
// 64 lanes x 4 dims/lane = 256 dims; per edge one coalesced 512B z-row read.
// Accumulators lane-private -> zero cross-lane reduction in the sum phase.
// Edge sources preloaded coalesced (deg<=64) and broadcast via shfl.
// Tiny footprint (no LDS, ~32 VGPR) keeps occupancy high for latency hiding.
// ---------------------------------------------------------------------------
__global__ __launch_bounds__(256) void agg_kernel(
    const int* __restrict__ tgt4, const int* __restrict__ offsets4,
    const int* __restrict__ perm4, const float* __restrict__ el4,
    const float* __restrict__ er4, const u16* __restrict__ zb4,
    u16* __restrict__ metab4, int g0)
{
    int gy = blockIdx.y, g = g0 + gy;
    const int* tgt = tgt4 + (size_t)g * TT;
    const int* offsets = offsets4 + (size_t)g * (NPG + 1);
    const int* perm = perm4 + (size_t)g * EG;
    const float* el = el4 + (size_t)gy * NPG * 4;
    const float* er = er4 + (size_t)gy * NPG * 4;
    const u16* zb = zb4 + (size_t)gy * NPG * 256;
    u16* metab = metab4 + (size_t)g * TT * 256;
    int wv = threadIdx.x >> 6, lane = threadIdx.x & 63;
    int t = blockIdx.x * 4 + wv;
    int dstn = tgt[t];
    int start = offsets[dstn];
    int deg = offsets[dstn + 1] - start;
    // preload first 64 edge sources, one coalesced wave-load
    int pv = perm[start + (lane < deg ? lane : 0)];
    // ---- pass 1: max per head; lane covers head (lane&3), edges (lane>>2)+16k
    int h1 = lane & 3, e0 = lane >> 2;
    float erv1 = er[dstn * 4 + h1];
    float mx = -INFINITY;
    for (int ee = e0; ee < deg; ee += 16) {
        int s = (ee < 64) ? __shfl(pv, ee) : perm[start + ee];
        float v = el[s * 4 + h1] + erv1;
        v = fmaxf(v, 0.2f * v);
        mx = fmaxf(mx, v);
    }
#pragma unroll
    for (int o = 4; o < 64; o <<= 1) mx = fmaxf(mx, __shfl_xor(mx, o));
    // ---- pass 2: sequential edges; lane owns dims [lane*4, lane*4+4) ----
    int h2 = lane >> 4;
    float mxh = __shfl(mx, h2);            // lane h2 holds head-h2 max
    float erv2 = er[dstn * 4 + h2];
    const u16* zrow = zb + (size_t)lane * 4;
    float a0 = 0.f, a1 = 0.f, a2 = 0.f, a3 = 0.f, denom = 0.f;
    for (int it = 0; it < deg; ++it) {
        int s = (it < 64) ? __shfl(pv, it) : perm[start + it];
        float v = el[s * 4 + h2] + erv2;
        v = fmaxf(v, 0.2f * v);
        float ex = __expf(v - mxh);
        denom += ex;
        uint2 w = *(const uint2*)&zrow[(size_t)s * 256];
        a0 += ex * uplo(w.x); a1 += ex * uphi(w.x);
        a2 += ex * uplo(w.y); a3 += ex * uphi(w.y);
    }
    // ---- epilogue: lane-private, no reduction ----
    float inv = __builtin_amdgcn_rcpf(denom + 1e-9f);
    float v0 = a0 * inv, v1 = a1 * inv, v2 = a2 * inv, v3 = a3 * inv;
    v0 = v0 > 0.f ? v0 : (__expf(v0) - 1.f);
    v1 = v1 > 0.f ? v1 : (__expf(v1) - 1.f);
    v2 = v2 > 0.f ? v2 : (__expf(v2) - 1.f);
    v3 = v3 > 0.f ? v3 : (__expf(v3) - 1.f);
    uint2 mw;
    mw.x = pk2(v0, v1); mw.y = pk2(v2, v3);
    *(uint2*)&metab[(size_t)t * 256 + lane * 4] = mw;
}

// ---------------------------------------------------------------------------
// Semantic logits, batched over all 4 graphs (y=g). N-quarters looped
// IN-BLOCK with A-fragments register-resident (A fetched once from HBM).
// wsum[g] += sum_t tanh(meta[g][t]@W[b] + b)@q
// ---------------------------------------------------------------------------
__global__ __launch_bounds__(256) void sem_kernel(
    const u16* __restrict__ metab4, const u16* __restrict__ semWb,
    const float* __restrict__ semb, const float* __restrict__ semq,
    float* __restrict__ wsum4)
{
    __shared__ short Bs[64 * 264];
    __shared__ float bsum;
    int g = blockIdx.y, b = g >> 1;
    const u16* A = metab4 + (size_t)g * TT * 256;
    int tid = threadIdx.x, wv = tid >> 6, l = tid & 63, q = l >> 4, c = l & 15;
    if (tid == 0) bsum = 0.f;
    int rbase = blockIdx.x * 64;
    int row = rbase + wv * 16 + c;
    bool ok = row < TT;
    short8 af[8];
    const u16* Ap = A + (size_t)row * 256 + q * 8;
#pragma unroll
    for (int s = 0; s < 8; ++s)
        af[s] = ok ? *(const short8*)(Ap + 32 * s) : (short8)(short)0;
    float part = 0.f;
    int grl = rbase + wv * 16 + q * 4;
    for (int nq = 0; nq < 4; ++nq) {
        const u16* W = semWb + b * 65536 + nq * 16384;
        short8 bv[8];
#pragma unroll
        for (int j = 0; j < 8; ++j)
            bv[j] = *(const short8*)&W[(tid + 256 * j) * 8];
        __syncthreads();          // previous quarter's Bs reads done
#pragma unroll
        for (int j = 0; j < 8; ++j) {
            int e = tid + 256 * j, r = e >> 5, kc = (e & 31) * 8;
            *(short8*)&Bs[r * 264 + kc] = bv[j];
        }
        __syncthreads();
        f32x4 acc[4];
#pragma unroll
        for (int i = 0; i < 4; ++i) acc[i] = (f32x4){0.f, 0.f, 0.f, 0.f};
#pragma unroll
        for (int s = 0; s < 8; ++s)
#pragma unroll
            for (int t4 = 0; t4 < 4; ++t4)
                acc[t4] = MFMA16(af[s],
                    *(const short8*)&Bs[(t4 * 16 + c) * 264 + q * 8 + 32 * s], acc[t4]);
#pragma unroll
        for (int t4 = 0; t4 < 4; ++t4) {
            int col = nq * 64 + t4 * 16 + c;
            float bb = semb[b * 256 + col], qq = semq[b * 256 + col];
#pragma unroll
            for (int reg = 0; reg < 4; ++reg)
                if (grl + reg < TT) part += ftanh(acc[t4][reg] + bb) * qq;
        }
    }
    for (int o = 32; o > 0; o >>= 1) part += __shfl_xor(part, o);
    if (l == 0) atomicAdd(&bsum, part);
    __syncthreads();
    if (tid == 0) atomicAdd(&wsum4[g], bsum);
}

// ---------------------------------------------------------------------------
// Output, batched over branches (y=b): beta = softmax(wsum[b*2..]/T);
// s = b0*meta0+b1*meta1; out = s@foW + fob
// ---------------------------------------------------------------------------
__global__ __launch_bounds__(256) void out_kernel(
    const u16* __restrict__ metab4, const float* __restrict__ wsum4,
    const u16* __restrict__ foWb, const float* __restrict__ fob,
    float* __restrict__ out)
{
    __shared__ short Bs[64 * 264];
    int b = blockIdx.y;
    int tid = threadIdx.x, wv = tid >> 6, l = tid & 63, q = l >> 4, c = l & 15;
    float w0 = wsum4[b * 2] * (1.f / TT), w1 = wsum4[b * 2 + 1] * (1.f / TT);
    float mxv = fmaxf(w0, w1);
    float e0 = __expf(w0 - mxv), e1 = __expf(w1 - mxv);
    float inv = 1.f / (e0 + e1);
    float b0 = e0 * inv, b1 = e1 * inv;
    const u16* W = foWb + b * 16384;
    short8 bv[8];
#pragma unroll
    for (int j = 0; j < 8; ++j)
        bv[j] = *(const short8*)&W[(tid + 256 * j) * 8];
    int rbase = blockIdx.x * 64;
    int row = rbase + wv * 16 + c;
    bool ok = row < TT;
    const u16* Ap0 = metab4 + (size_t)(b * 2) * TT * 256 + (size_t)row * 256 + q * 8;
    const u16* Ap1 = Ap0 + (size_t)TT * 256;
    short8 af[8];
#pragma unroll
    for (int half = 0; half < 2; ++half) {
        union { short8 s8; uint4 u; } ua[4], uc[4];
#pragma unroll
        for (int s = 0; s < 4; ++s) {
            int ss = half * 4 + s;
            ua[s].s8 = ok ? *(const short8*)(Ap0 + 32 * ss) : (short8)(short)0;
            uc[s].s8 = ok ? *(const short8*)(Ap1 + 32 * ss) : (short8)(short)0;
        }
        if (half == 0) {
#pragma unroll
            for (int j = 0; j < 8; ++j) {
                int e = tid + 256 * j, r = e >> 5, kc = (e & 31) * 8;
                *(short8*)&Bs[r * 264 + kc] = bv[j];
            }
        }
#pragma unroll
        for (int s = 0; s < 4; ++s) {
            float4 a0 = up4(ua[s].u.x, ua[s].u.y), a1 = up4(ua[s].u.z, ua[s].u.w);
            float4 c0 = up4(uc[s].u.x, uc[s].u.y), c1 = up4(uc[s].u.z, uc[s].u.w);
            float4 v0, v1;
            v0.x = b0 * a0.x + b1 * c0.x; v0.y = b0 * a0.y + b1 * c0.y;
            v0.z = b0 * a0.z + b1 * c0.z; v0.w = b0 * a0.w + b1 * c0.w;
            v1.x = b0 * a1.x + b1 * c1.x; v1.y = b0 * a1.y + b1 * c1.y;
            v1.z = b0 * a1.z + b1 * c1.z; v1.w = b0 * a1.w + b1 * c1.w;
            af[half * 4 + s] = cvt8(v0, v1);
        }
    }
    __syncthreads();
    f32x4 acc[4];
#pragma unroll
    for (int i = 0; i < 4; ++i) acc[i] = (f32x4){0.f, 0.f, 0.f, 0.f};
#pragma unroll
    for (int s = 0; s < 8; ++s)
#pragma unroll
        for (int t4 = 0; t4 < 4; ++t4)
            acc[t4] = MFMA16(af[s],
                *(const short8*)&Bs[(t4 * 16 + c) * 264 + q * 8 + 32 * s], acc[t4]);
    int grl = rbase + wv * 16 + q * 4;
#pragma unroll
    for (int t4 = 0; t4 < 4; ++t4) {
        int col = t4 * 16 + c;
        float bvv = fob[b * 64 + col];
#pragma unroll
        for (int reg = 0; reg < 4; ++reg) {
            int gr = grl + reg;
            if (gr < TT)
                out[(size_t)b * TT * 64 + (size_t)gr * 64 + col] = acc[t4][reg] + bvv;
        }
    }
}

// ---------------------------------------------------------------------------
extern "C" void kernel_launch(void* const* d_in, const int* in_sizes, int n_in,
                              void* d_out, int out_size, void* d_ws, size_t ws_size,
                              hipStream_t stream)
{
    const float* f0    = (const float*)d_in[0];
    const float* f1    = (const float*)d_in[1];
    const float* fcW   = (const float*)d_in[2];
    const float* fcb   = (const float*)d_in[3];
    const float* gatW  = (const float*)d_in[4];
    const float* al    = (const float*)d_in[5];
    const float* ar    = (const float*)d_in[6];
    const float* semW  = (const float*)d_in[7];
    const float* semb  = (const float*)d_in[8];
    const float* semq  = (const float*)d_in[9];
    const float* foW   = (const float*)d_in[10];
    const float* fob   = (const float*)d_in[11];
    const int* type_idx = (const int*)d_in[12];
    const int* node_idx = (const int*)d_in[13];
    const int* edge_src = (const int*)d_in[14];
    const int* edge_dst = (const int*)d_in[15];
    const int* tgt_idx  = (const int*)d_in[16];
    float* out = (float*)d_out;

    char* ws = (char*)d_ws;
    size_t off = 0;
    auto alloc = [&](size_t bytes) -> void* {
        void* p = ws + off;
        off = (off + bytes + 255) & ~(size_t)255;
        return p;
    };
    // fixed allocations first
    u16*   tbf         = (u16*)alloc((size_t)NT * 64 * 2);
    u16*   metab4      = (u16*)alloc((size_t)4 * TT * 256 * 2);
    float* wsum4       = (float*)alloc(64);
    u16*   fcWb        = (u16*)alloc(32768 * 2);
    u16*   gatWb       = (u16*)alloc(65536 * 2);
    u16*   semWb       = (u16*)alloc(131072 * 2);
    u16*   foWb        = (u16*)alloc(32768 * 2);
    int*   deg4        = (int*)alloc((size_t)4 * NPG * 4);
    int*   tflag4      = (int*)alloc((size_t)4 * NPG * 4);
    int*   offsets4    = (int*)alloc((size_t)4 * (NPG + 1) * 4);
    int*   cursor4     = (int*)alloc((size_t)4 * NPG * 4);
    int*   perm4       = (int*)alloc((size_t)4 * EG * 4);
    int*   part4       = (int*)alloc((size_t)4 * NPB * 4);
    int*   pref4       = (int*)alloc((size_t)4 * NPB * 4);
    // graph-batched buffers: as many graphs per batch as workspace allows
    const size_t perg = (size_t)NPG * 256 * 2 + 2 * (size_t)NPG * 4 * 4 + 768;
    int GPB = 1;
    {
        size_t rem = (ws_size > off) ? ws_size - off : 0;
        if (rem >= 4 * perg) GPB = 4;
        else if (rem >= 2 * perg) GPB = 2;
    }
    u16*   zb          = (u16*)alloc((size_t)GPB * NPG * 256 * 2);
    float* el          = (float*)alloc((size_t)GPB * NPG * 4 * 4);
    float* er          = (float*)alloc((size_t)GPB * NPG * 4 * 4);

    const int eblocks = (EG + 255) / 256;
    const int tblocks = (TT + 255) / 256;

    prep_kernel<<<512, 256, 0, stream>>>(fcW, gatW, semW, foW,
                                         fcWb, gatWb, semWb, foWb);

    // --- batched target-only CSR build for all 4 graphs ---
    hipMemsetAsync(deg4, 0, (size_t)4 * NPG * 4, stream);
    hipMemsetAsync(tflag4, 0, (size_t)4 * NPG * 4, stream);
    hipMemsetAsync(wsum4, 0, 16, stream);
    mark_kernel<<<dim3(tblocks, 4), 256, 0, stream>>>(tgt_idx, tflag4);
    count4_kernel<<<dim3(eblocks, 4), 256, 0, stream>>>(edge_dst, tflag4, deg4);
    partial4_kernel<<<dim3(NPB, 4), 256, 0, stream>>>(deg4, part4);
    scanp_kernel<<<dim3(1, 4), 256, 0, stream>>>(part4, pref4, offsets4);
    distribute_kernel<<<dim3(NPB, 4), 256, 0, stream>>>(deg4, pref4, offsets4,
                                                        cursor4);
    scatter4_kernel<<<dim3(eblocks, 4), 256, 0, stream>>>(edge_dst, edge_src,
                                                          tflag4, cursor4, perm4);

    fc_kernel<<<dim3(782, 2), 256, 0, stream>>>(f0, f1, fcWb, fcb, type_idx, tbf);
    for (int g0 = 0; g0 < 4; g0 += GPB) {
        z_kernel<<<dim3(782, GPB), 256, 0, stream>>>(
            tbf, node_idx, gatWb, al, ar, zb, el, er, g0);
        agg_kernel<<<dim3(TT / 4, GPB), 256, 0, stream>>>(
            tgt_idx, offsets4, perm4, el, er, zb, metab4, g0);
    }
    sem_kernel<<<dim3(313, 4), 256, 0, stream>>>(metab4, semWb, semb, semq,
                                                 wsum4);
    out_kernel<<<dim3(313, 2), 256, 0, stream>>>(metab4, wsum4, foWb, fob, out);
}

// Round 4
// 444.987 us; speedup vs baseline: 1.2509x; 1.0435x over previous
//
#include <hip/hip_runtime.h>
#include <math.h>

#define NT     100000   // total nodes
#define NPT    50000    // nodes per type
#define NPG    50000    // nodes per metapath graph
#define EG     500000   // edges per graph
#define DD     256      // NH*HD
#define TT     20000    // targets per metapath
#define NPB    196      // scan partial blocks per graph (196*256 >= 50000)

typedef __attribute__((ext_vector_type(8))) short short8;   // 8 bf16 = 4 VGPRs
typedef __attribute__((ext_vector_type(4))) float f32x4;    // MFMA C/D
typedef unsigned short u16;

#define MFMA16(a, b, c) __builtin_amdgcn_mfma_f32_16x16x32_bf16((a), (b), (c), 0, 0, 0)

// RNE float->bf16 helpers
__device__ inline unsigned pk2(float x, float y) {
    unsigned a = __float_as_uint(x); a = (a + 0x7FFFu + ((a >> 16) & 1u)) >> 16;
    unsigned b = __float_as_uint(y); b = (b + 0x7FFFu + ((b >> 16) & 1u)) >> 16;
    return (a & 0xFFFFu) | (b << 16);
}
__device__ inline u16 pkb(float x) {
    unsigned a = __float_as_uint(x);
    return (u16)((a + 0x7FFFu + ((a >> 16) & 1u)) >> 16);
}
__device__ inline short8 cvt8(float4 a, float4 b) {
    union { int4 i; short8 s; } u;
    u.i = make_int4((int)pk2(a.x, a.y), (int)pk2(a.z, a.w),
                    (int)pk2(b.x, b.y), (int)pk2(b.z, b.w));
    return u.s;
}
__device__ inline float4 up4(unsigned lo, unsigned hi) {
    float4 r;
    r.x = __uint_as_float(lo << 16);
    r.y = __uint_as_float(lo & 0xFFFF0000u);
    r.z = __uint_as_float(hi << 16);
    r.w = __uint_as_float(hi & 0xFFFF0000u);
    return r;
}
__device__ inline float uplo(unsigned w) { return __uint_as_float(w << 16); }
__device__ inline float uphi(unsigned w) { return __uint_as_float(w & 0xFFFF0000u); }
// fast tanh: 1 - 2/(e^{2x}+1) via v_exp_f32 + v_rcp_f32 (rel err ~1e-6)
__device__ inline float ftanh(float x) {
    float e = __expf(2.f * x);
    return 1.f - 2.f * __builtin_amdgcn_rcpf(e + 1.f);
}

// ---------------------------------------------------------------------------
// prep: convert all weights to bf16, transposing to [n][k] where needed.
// ---------------------------------------------------------------------------
__global__ __launch_bounds__(256) void prep_kernel(
    const float* __restrict__ fcW, const float* __restrict__ gatW,
    const float* __restrict__ semW, const float* __restrict__ foW,
    u16* __restrict__ fcWb, u16* __restrict__ gatWb,
    u16* __restrict__ semWb, u16* __restrict__ foWb)
{
    int i = blockIdx.x * 256 + threadIdx.x;
    if (i < 32768) fcWb[i] = pkb(fcW[i]);
    if (i < 65536) {
        int g = i >> 14, rem = i & 16383, n = rem >> 6, k = rem & 63;
        gatWb[i] = pkb(gatW[g * 16384 + k * 256 + n]);
    }
    if (i < 131072) {
        int b = i >> 16, rem = i & 65535, n = rem >> 8, k = rem & 255;
        semWb[i] = pkb(semW[b * 65536 + k * 256 + n]);
    }
    if (i < 32768) {
        int b = i >> 14, rem = i & 16383, n = rem >> 8, k = rem & 255;
        foWb[i] = pkb(foW[b * 16384 + k * 64 + n]);
    }
}

// ---------------------------------------------------------------------------
// fc: tbf[type_idx[ty][r]] = bf16(features_ty @ fc_W[ty]^T + fc_b[ty])
// A loaded flat-coalesced (1 KiB per wave-instr), converted to bf16,
// staged via XOR-swizzled LDS; B staged likewise. LDS = exactly 64 KiB.
// ---------------------------------------------------------------------------
__global__ __launch_bounds__(256) void fc_kernel(
    const float* __restrict__ f0, const float* __restrict__ f1,
    const u16* __restrict__ fcWb, const float* __restrict__ fcb,
    const int* __restrict__ type_idx, u16* __restrict__ tbf)
{
    __shared__ short As[64 * 256];   // swizzled [row][col^((row&15)<<3)]
    __shared__ short Bs[64 * 256];
    int ty = blockIdx.y;
    const float* feat = ty ? f1 : f0;
    const u16* W = fcWb + ty * 64 * 256;
    int tid = threadIdx.x, wv = tid >> 6, l = tid & 63, q = l >> 4, c = l & 15;
    int rbase = blockIdx.x * 64;
    // ---- B: coalesced register load ----
    short8 bv[8];
#pragma unroll
    for (int j = 0; j < 8; ++j)
        bv[j] = *(const short8*)&W[(tid + 256 * j) * 8];
    // ---- A: flat coalesced f32 loads, convert, stage (2 halves) ----
    const float* Abase = feat + (size_t)rbase * 256;
#pragma unroll
    for (int half = 0; half < 2; ++half) {
        float4 va[8];
#pragma unroll
        for (int j = 0; j < 8; ++j) {
            int fi = tid + 256 * (half * 8 + j);       // float4 index in tile
            bool okA = (rbase + (fi >> 6)) < NPT;
            va[j] = okA ? *(const float4*)(Abase + (size_t)fi * 4)
                        : (float4){0.f, 0.f, 0.f, 0.f};
        }
#pragma unroll
        for (int j = 0; j < 8; ++j) {
            int fi = tid + 256 * (half * 8 + j);
            int r = fi >> 6, cs = (fi & 63) * 4;       // 4-short store
            int2 v = make_int2((int)pk2(va[j].x, va[j].y),
                               (int)pk2(va[j].z, va[j].w));
            *(int2*)&As[r * 256 + (cs ^ ((r & 15) << 3))] = v;
        }
    }
    // ---- B -> LDS (swizzled) ----
#pragma unroll
    for (int j = 0; j < 8; ++j) {
        int e = tid + 256 * j, r = e >> 5, cs = (e & 31) * 8;
        *(short8*)&Bs[r * 256 + (cs ^ ((r & 15) << 3))] = bv[j];
    }
    __syncthreads();
    // ---- A fragments from LDS ----
    short8 af[8];
    int arow = wv * 16 + c;                            // arow & 15 == c
#pragma unroll
    for (int s = 0; s < 8; ++s)
        af[s] = *(const short8*)&As[arow * 256 + ((q * 8 + 32 * s) ^ (c << 3))];
    f32x4 acc[4];
#pragma unroll
    for (int i = 0; i < 4; ++i) acc[i] = (f32x4){0.f, 0.f, 0.f, 0.f};
#pragma unroll
    for (int s = 0; s < 8; ++s)
#pragma unroll
        for (int t4 = 0; t4 < 4; ++t4)
            acc[t4] = MFMA16(af[s],
                *(const short8*)&Bs[(t4 * 16 + c) * 256 +
                                    ((q * 8 + 32 * s) ^ (c << 3))], acc[t4]);
    int grl = rbase + wv * 16 + q * 4;
#pragma unroll
    for (int t4 = 0; t4 < 4; ++t4) {
        int col = t4 * 16 + c;
        float bvv = fcb[ty * 64 + col];
#pragma unroll
        for (int reg = 0; reg < 4; ++reg) {
            int gr = grl + reg;
            if (gr < NPT) {
                int dest = type_idx[ty * NPT + gr];
                tbf[(size_t)dest * 64 + col] = pkb(acc[t4][reg] + bvv);
            }
        }
    }
}

// ---------------------------------------------------------------------------
// z = tbf[node_idx] @ gat_W (bf16 out), fused el/er epilogue (fp32).
// Batched over graphs via blockIdx.y (graph g0+y; buffers indexed by y).
// ---------------------------------------------------------------------------
__global__ __launch_bounds__(256) void z_kernel(
    const u16* __restrict__ tbf, const int* __restrict__ nidx4,
    const u16* __restrict__ gatWb4, const float* __restrict__ al4,
    const float* __restrict__ ar4, u16* __restrict__ zb4,
    float* __restrict__ el4, float* __restrict__ er4, int g0)
{
    __shared__ short Bs[256 * 72];
    int gy = blockIdx.y, g = g0 + gy;
    const int* nidx = nidx4 + (size_t)g * NPG;
    const u16* gatWb = gatWb4 + (size_t)g * 16384;
    const float* al = al4 + g * 256;
    const float* ar = ar4 + g * 256;
    u16* zb = zb4 + (size_t)gy * NPG * 256;
    float* el = el4 + (size_t)gy * NPG * 4;
    float* er = er4 + (size_t)gy * NPG * 4;
    int tid = threadIdx.x, wv = tid >> 6, l = tid & 63, q = l >> 4, c = l & 15;
    short8 bv[8];
#pragma unroll
    for (int j = 0; j < 8; ++j)
        bv[j] = *(const short8*)&gatWb[(tid + 256 * j) * 8];
    int rbase = blockIdx.x * 64;
    int row = rbase + wv * 16 + c;
    bool ok = row < NPG;
    short8 af0 = (short8)(short)0, af1 = (short8)(short)0;
    if (ok) {
        int n = nidx[row];
        const u16* Ap = tbf + (size_t)n * 64 + q * 8;
        af0 = *(const short8*)(Ap);
        af1 = *(const short8*)(Ap + 32);
    }
#pragma unroll
    for (int j = 0; j < 8; ++j) {
        int e = tid + 256 * j, r = e >> 3, kc = (e & 7) * 8;
        *(short8*)&Bs[r * 72 + kc] = bv[j];
    }
    __syncthreads();
    f32x4 acc[16];
    const f32x4 zero = (f32x4){0.f, 0.f, 0.f, 0.f};
#pragma unroll
    for (int t16 = 0; t16 < 16; ++t16) {
        const short* Bp = &Bs[(t16 * 16 + c) * 72 + q * 8];
        acc[t16] = MFMA16(af0, *(const short8*)&Bp[0], zero);
        acc[t16] = MFMA16(af1, *(const short8*)&Bp[32], acc[t16]);
    }
    int grl = rbase + wv * 16 + q * 4;
#pragma unroll
    for (int t16 = 0; t16 < 16; ++t16)
#pragma unroll
        for (int reg = 0; reg < 4; ++reg) {
            int gr = grl + reg;
            if (gr < NPG)
                zb[(size_t)gr * 256 + t16 * 16 + c] = pkb(acc[t16][reg]);
        }
    float pl[4][4], pr[4][4];
#pragma unroll
    for (int reg = 0; reg < 4; ++reg)
#pragma unroll
        for (int h = 0; h < 4; ++h) { pl[reg][h] = 0.f; pr[reg][h] = 0.f; }
#pragma unroll
    for (int t16 = 0; t16 < 16; ++t16) {
        int col = t16 * 16 + c, h = t16 >> 2;
        float alv = al[col], arv = ar[col];
#pragma unroll
        for (int reg = 0; reg < 4; ++reg) {
            pl[reg][h] += acc[t16][reg] * alv;
            pr[reg][h] += acc[t16][reg] * arv;
        }
    }
#pragma unroll
    for (int o = 1; o < 16; o <<= 1)
#pragma unroll
        for (int reg = 0; reg < 4; ++reg)
#pragma unroll
            for (int h = 0; h < 4; ++h) {
                pl[reg][h] += __shfl_xor(pl[reg][h], o);
                pr[reg][h] += __shfl_xor(pr[reg][h], o);
            }
    if (c == 0) {
#pragma unroll
        for (int reg = 0; reg < 4; ++reg) {
            int gr = grl + reg;
            if (gr < NPG) {
                float4 vl = {pl[reg][0], pl[reg][1], pl[reg][2], pl[reg][3]};
                float4 vr = {pr[reg][0], pr[reg][1], pr[reg][2], pr[reg][3]};
                *(float4*)&el[gr * 4] = vl;
                *(float4*)&er[gr * 4] = vr;
            }
        }
    }
}

// ---------------------------------------------------------------------------
// CSR build over TARGET nodes only, batched over all 4 graphs.
// ---------------------------------------------------------------------------
__global__ __launch_bounds__(256) void mark_kernel(
    const int* __restrict__ tgt, int* __restrict__ tflag4)
{
    int g = blockIdx.y;
    int i = blockIdx.x * 256 + threadIdx.x;
    if (i < TT) tflag4[g * NPG + tgt[(size_t)g * TT + i]] = 1;
}

__global__ __launch_bounds__(256) void count4_kernel(
    const int* __restrict__ dst, const int* __restrict__ tflag4,
    int* __restrict__ deg4)
{
    int g = blockIdx.y;
    int e = blockIdx.x * 256 + threadIdx.x;
    if (e < EG) {
        int d = dst[(size_t)g * EG + e];
        if (tflag4[g * NPG + d]) atomicAdd(&deg4[g * NPG + d], 1);
    }
}

__device__ inline int block_excl_scan(int v, int tid) {
    __shared__ int wtot[4];
    int lane = tid & 63, w = tid >> 6;
    int x = v;
#pragma unroll
    for (int o = 1; o < 64; o <<= 1) {
        int y = __shfl_up(x, o);
        if (lane >= o) x += y;
    }
    if (lane == 63) wtot[w] = x;
    __syncthreads();
    if (tid == 0) {
        int s = 0;
#pragma unroll
        for (int i = 0; i < 4; ++i) { int t = wtot[i]; wtot[i] = s; s += t; }
    }
    __syncthreads();
    return wtot[w] + x - v;
}

__global__ __launch_bounds__(256) void partial4_kernel(
    const int* __restrict__ deg4, int* __restrict__ part4)
{
    int g = blockIdx.y;
    int i = blockIdx.x * 256 + threadIdx.x;
    int v = (i < NPG) ? deg4[g * NPG + i] : 0;
#pragma unroll
    for (int o = 32; o > 0; o >>= 1) v += __shfl_xor(v, o);
    __shared__ int ws4[4];
    if ((threadIdx.x & 63) == 0) ws4[threadIdx.x >> 6] = v;
    __syncthreads();
    if (threadIdx.x == 0)
        part4[g * NPB + blockIdx.x] = ws4[0] + ws4[1] + ws4[2] + ws4[3];
}

__global__ __launch_bounds__(256) void scanp_kernel(
    const int* __restrict__ part4, int* __restrict__ pref4,
    int* __restrict__ offsets4)
{
    int g = blockIdx.y;
    int t = threadIdx.x;
    int v = (t < NPB) ? part4[g * NPB + t] : 0;
    int e = block_excl_scan(v, t);
    if (t < NPB) pref4[g * NPB + t] = e;
    if (t == 255) offsets4[(size_t)g * (NPG + 1) + NPG] = e + v;  // total
}

__global__ __launch_bounds__(256) void distribute_kernel(
    const int* __restrict__ deg4, const int* __restrict__ pref4,
    int* __restrict__ offsets4, int* __restrict__ cursor4)
{
    int g = blockIdx.y;
    int i = blockIdx.x * 256 + threadIdx.x;
    int v = (i < NPG) ? deg4[g * NPG + i] : 0;
    int e = block_excl_scan(v, threadIdx.x);
    if (i < NPG) {
        int off = pref4[g * NPB + blockIdx.x] + e;
        offsets4[(size_t)g * (NPG + 1) + i] = off;
        cursor4[g * NPG + i] = off;
    }
}

__global__ __launch_bounds__(256) void scatter4_kernel(
    const int* __restrict__ dst, const int* __restrict__ src,
    const int* __restrict__ tflag4, int* __restrict__ cursor4,
    int* __restrict__ perm4)
{
    int g = blockIdx.y;
    int e = blockIdx.x * 256 + threadIdx.x;
    if (e < EG) {
        int d = dst[(size_t)g * EG + e];
        if (tflag4[g * NPG + d]) {
            int pos = atomicAdd(&cursor4[g * NPG + d], 1);
            perm4[(size_t)g * EG + pos] = src[(size_t)g * EG + e];
        }
    }
}

// ---------------------------------------------------------------------------
// escore: per-edge el gather, hoisted out of agg's serial per-target loop.
// elp[i][h] = el[perm[i]][h]; embarrassingly parallel, el is L2-resident.
// ---------------------------------------------------------------------------
__global__ __launch_bounds__(256) void escore_kernel(
    const int* __restrict__ perm4, const int* __restrict__ offsets4,
    const float* __restrict__ el4, float* __restrict__ elp4, int g0)
{
    int gy = blockIdx.y, g = g0 + gy;
    int i = blockIdx.x * 256 + threadIdx.x;
    int total = offsets4[(size_t)g * (NPG + 1) + NPG];
    if (i < total) {
        int s = perm4[(size_t)g * EG + i];
        const float4 v = *(const float4*)&el4[(size_t)gy * NPG * 4 + s * 4];
        *(float4*)&elp4[(size_t)gy * EG * 4 + (size_t)i * 4] = v;
    }
}

// ---------------------------------------------------------------------------
// Aggregation: ONE WAVE per target covering ALL 4 heads.
// 64 lanes x 4 dims/lane = 256 dims; per edge one coalesced 512B z-row read.
// Scores come from elp (coalesced / broadcast) when available; pass-2
// unrolled x2 so two z-row gathers are in flight per wave.
// ---------------------------------------------------------------------------
__global__ __launch_bounds__(256) void agg_kernel(
    const int* __restrict__ tgt4, const int* __restrict__ offsets4,
    const int* __restrict__ perm4, const float* __restrict__ elp4,
    const float* __restrict__ el4, const float* __restrict__ er4,
    const u16* __restrict__ zb4, u16* __restrict__ metab4, int g0)
{
    int gy = blockIdx.y, g = g0 + gy;
    const int* tgt = tgt4 + (size_t)g * TT;
    const int* offsets = offsets4 + (size_t)g * (NPG + 1);
    const int* perm = perm4 + (size_t)g * EG;
    const float* el = el4 + (size_t)gy * NPG * 4;
    const float* er = er4 + (size_t)gy * NPG * 4;
    const float* elp = elp4 ? elp4 + (size_t)gy * EG * 4 : (const float*)0;
    const u16* zb = zb4 + (size_t)gy * NPG * 256;
    u16* metab = metab4 + (size_t)g * TT * 256;
    int wv = threadIdx.x >> 6, lane = threadIdx.x & 63;
    int t = blockIdx.x * 4 + wv;
    int dstn = tgt[t];
    int start = offsets[dstn];
    int deg = offsets[dstn + 1] - start;
    // preload first 64 edge sources, one coalesced wave-load
    int pv = perm[start + (lane < deg ? lane : 0)];
    int h1 = lane & 3, e0 = lane >> 2;
    float erv1 = er[dstn * 4 + h1];
    float mx = -INFINITY;
    int h2 = lane >> 4;
    float erv2 = er[dstn * 4 + h2];
    const u16* zrow = zb + (size_t)lane * 4;
    float a0 = 0.f, a1 = 0.f, a2 = 0.f, a3 = 0.f, denom = 0.f;

    if (elp) {
        // ---- pass 1: coalesced score read (first 16 edges in ONE load) ----
        for (int ee = e0; ee < deg; ee += 16) {
            float v = elp[(start + ee) * 4 + h1] + erv1;
            v = fmaxf(v, 0.2f * v);
            mx = fmaxf(mx, v);
        }
#pragma unroll
        for (int o = 4; o < 64; o <<= 1) mx = fmaxf(mx, __shfl_xor(mx, o));
        float mxh = __shfl(mx, h2);
        // ---- pass 2: unrolled x2, two z-rows in flight ----
        int it = 0;
        for (; it + 2 <= deg; it += 2) {
            int s0 = (it < 64) ? __shfl(pv, it) : perm[start + it];
            int s1 = (it + 1 < 64) ? __shfl(pv, it + 1) : perm[start + it + 1];
            float sv0 = elp[(start + it) * 4 + h2];
            float sv1 = elp[(start + it + 1) * 4 + h2];
            uint2 w0 = *(const uint2*)&zrow[(size_t)s0 * 256];
            uint2 w1 = *(const uint2*)&zrow[(size_t)s1 * 256];
            float v0 = sv0 + erv2; v0 = fmaxf(v0, 0.2f * v0);
            float v1 = sv1 + erv2; v1 = fmaxf(v1, 0.2f * v1);
            float ex0 = __expf(v0 - mxh), ex1 = __expf(v1 - mxh);
            denom += ex0 + ex1;
            a0 += ex0 * uplo(w0.x) + ex1 * uplo(w1.x);
            a1 += ex0 * uphi(w0.x) + ex1 * uphi(w1.x);
            a2 += ex0 * uplo(w0.y) + ex1 * uplo(w1.y);
            a3 += ex0 * uphi(w0.y) + ex1 * uphi(w1.y);
        }
        if (it < deg) {
            int s0 = (it < 64) ? __shfl(pv, it) : perm[start + it];
            float v0 = elp[(start + it) * 4 + h2] + erv2;
            v0 = fmaxf(v0, 0.2f * v0);
            float ex0 = __expf(v0 - mxh);
            denom += ex0;
            uint2 w0 = *(const uint2*)&zrow[(size_t)s0 * 256];
            a0 += ex0 * uplo(w0.x); a1 += ex0 * uphi(w0.x);
            a2 += ex0 * uplo(w0.y); a3 += ex0 * uphi(w0.y);
        }
    } else {
        // ---- fallback: gather el directly (round-3 path) ----
        for (int ee = e0; ee < deg; ee += 16) {
            int s = (ee < 64) ? __shfl(pv, ee) : perm[start + ee];
            float v = el[s * 4 + h1] + erv1;
            v = fmaxf(v, 0.2f * v);
            mx = fmaxf(mx, v);
        }
#pragma unroll
        for (int o = 4; o < 64; o <<= 1) mx = fmaxf(mx, __shfl_xor(mx, o));
        float mxh = __shfl(mx, h2);
        for (int it = 0; it < deg; ++it) {
            int s = (it < 64) ? __shfl(pv, it) : perm[start + it];
            float v = el[s * 4 + h2] + erv2;
            v = fmaxf(v, 0.2f * v);
            float ex = __expf(v - mxh);
            denom += ex;
            uint2 w = *(const uint2*)&zrow[(size_t)s * 256];
            a0 += ex * uplo(w.x); a1 += ex * uphi(w.x);
            a2 += ex * uplo(w.y); a3 += ex * uphi(w.y);
        }
    }
    // ---- epilogue: lane-private, no reduction ----
    float inv = __builtin_amdgcn_rcpf(denom + 1e-9f);
    float v0 = a0 * inv, v1 = a1 * inv, v2 = a2 * inv, v3 = a3 * inv;
    v0 = v0 > 0.f ? v0 : (__expf(v0) - 1.f);
    v1 = v1 > 0.f ? v1 : (__expf(v1) - 1.f);
    v2 = v2 > 0.f ? v2 : (__expf(v2) - 1.f);
    v3 = v3 > 0.f ? v3 : (__expf(v3) - 1.f);
    uint2 mw;
    mw.x = pk2(v0, v1); mw.y = pk2(v2, v3);
    *(uint2*)&metab[(size_t)t * 256 + lane * 4] = mw;
}

// ---------------------------------------------------------------------------
// Semantic logits, batched over all 4 graphs (y=g). N-quarters looped
// IN-BLOCK with A-fragments register-resident (A fetched once from HBM).
// wsum[g] += sum_t tanh(meta[g][t]@W[b] + b)@q
// ---------------------------------------------------------------------------
__global__ __launch_bounds__(256) void sem_kernel(
    const u16* __restrict__ metab4, const u16* __restrict__ semWb,
    const float* __restrict__ semb, const float* __restrict__ semq,
    float* __restrict__ wsum4)
{
    __shared__ short Bs[64 * 264];
    __shared__ float bsum;
    int g = blockIdx.y, b = g >> 1;
    const u16* A = metab4 + (size_t)g * TT * 256;
    int tid = threadIdx.x, wv = tid >> 6, l = tid & 63, q = l >> 4, c = l & 15;
    if (tid == 0) bsum = 0.f;
    int rbase = blockIdx.x * 64;
    int row = rbase + wv * 16 + c;
    bool ok = row < TT;
    short8 af[8];
    const u16* Ap = A + (size_t)row * 256 + q * 8;
#pragma unroll
    for (int s = 0; s < 8; ++s)
        af[s] = ok ? *(const short8*)(Ap + 32 * s) : (short8)(short)0;
    float part = 0.f;
    int grl = rbase + wv * 16 + q * 4;
    for (int nq = 0; nq < 4; ++nq) {
        const u16* W = semWb + b * 65536 + nq * 16384;
        short8 bv[8];
#pragma unroll
        for (int j = 0; j < 8; ++j)
            bv[j] = *(const short8*)&W[(tid + 256 * j) * 8];
        __syncthreads();          // previous quarter's Bs reads done
#pragma unroll
        for (int j = 0; j < 8; ++j) {
            int e = tid + 256 * j, r = e >> 5, kc = (e & 31) * 8;
            *(short8*)&Bs[r * 264 + kc] = bv[j];
        }
        __syncthreads();
        f32x4 acc[4];
#pragma unroll
        for (int i = 0; i < 4; ++i) acc[i] = (f32x4){0.f, 0.f, 0.f, 0.f};
#pragma unroll
        for (int s = 0; s < 8; ++s)
#pragma unroll
            for (int t4 = 0; t4 < 4; ++t4)
                acc[t4] = MFMA16(af[s],
                    *(const short8*)&Bs[(t4 * 16 + c) * 264 + q * 8 + 32 * s], acc[t4]);
#pragma unroll
        for (int t4 = 0; t4 < 4; ++t4) {
            int col = nq * 64 + t4 * 16 + c;
            float bb = semb[b * 256 + col], qq = semq[b * 256 + col];
#pragma unroll
            for (int reg = 0; reg < 4; ++reg)
                if (grl + reg < TT) part += ftanh(acc[t4][reg] + bb) * qq;
        }
    }
    for (int o = 32; o > 0; o >>= 1) part += __shfl_xor(part, o);
    if (l == 0) atomicAdd(&bsum, part);
    __syncthreads();
    if (tid == 0) atomicAdd(&wsum4[g], bsum);
}

// ---------------------------------------------------------------------------
// Output, batched over branches (y=b): beta = softmax(wsum[b*2..]/T);
// s = b0*meta0+b1*meta1; out = s@foW + fob
// ---------------------------------------------------------------------------
__global__ __launch_bounds__(256) void out_kernel(
    const u16* __restrict__ metab4, const float* __restrict__ wsum4,
    const u16* __restrict__ foWb, const float* __restrict__ fob,
    float* __restrict__ out)
{
    __shared__ short Bs[64 * 264];
    int b = blockIdx.y;
    int tid = threadIdx.x, wv = tid >> 6, l = tid & 63, q = l >> 4, c = l & 15;
    float w0 = wsum4[b * 2] * (1.f / TT), w1 = wsum4[b * 2 + 1] * (1.f / TT);
    float mxv = fmaxf(w0, w1);
    float e0 = __expf(w0 - mxv), e1 = __expf(w1 - mxv);
    float inv = 1.f / (e0 + e1);
    float b0 = e0 * inv, b1 = e1 * inv;
    const u16* W = foWb + b * 16384;
    short8 bv[8];
#pragma unroll
    for (int j = 0; j < 8; ++j)
        bv[j] = *(const short8*)&W[(tid + 256 * j) * 8];
    int rbase = blockIdx.x * 64;
    int row = rbase + wv * 16 + c;
    bool ok = row < TT;
    const u16* Ap0 = metab4 + (size_t)(b * 2) * TT * 256 + (size_t)row * 256 + q * 8;
    const u16* Ap1 = Ap0 + (size_t)TT * 256;
    short8 af[8];
#pragma unroll
    for (int half = 0; half < 2; ++half) {
        union { short8 s8; uint4 u; } ua[4], uc[4];
#pragma unroll
        for (int s = 0; s < 4; ++s) {
            int ss = half * 4 + s;
            ua[s].s8 = ok ? *(const short8*)(Ap0 + 32 * ss) : (short8)(short)0;
            uc[s].s8 = ok ? *(const short8*)(Ap1 + 32 * ss) : (short8)(short)0;
        }
        if (half == 0) {
#pragma unroll
            for (int j = 0; j < 8; ++j) {
                int e = tid + 256 * j, r = e >> 5, kc = (e & 31) * 8;
                *(short8*)&Bs[r * 264 + kc] = bv[j];
            }
        }
#pragma unroll
        for (int s = 0; s < 4; ++s) {
            float4 a0 = up4(ua[s].u.x, ua[s].u.y), a1 = up4(ua[s].u.z, ua[s].u.w);
            float4 c0 = up4(uc[s].u.x, uc[s].u.y), c1 = up4(uc[s].u.z, uc[s].u.w);
            float4 v0, v1;
            v0.x = b0 * a0.x + b1 * c0.x; v0.y = b0 * a0.y + b1 * c0.y;
            v0.z = b0 * a0.z + b1 * c0.z; v0.w = b0 * a0.w + b1 * c0.w;
            v1.x = b0 * a1.x + b1 * c1.x; v1.y = b0 * a1.y + b1 * c1.y;
            v1.z = b0 * a1.z + b1 * c1.z; v1.w = b0 * a1.w + b1 * c1.w;
            af[half * 4 + s] = cvt8(v0, v1);
        }
    }
    __syncthreads();
    f32x4 acc[4];
#pragma unroll
    for (int i = 0; i < 4; ++i) acc[i] = (f32x4){0.f, 0.f, 0.f, 0.f};
#pragma unroll
    for (int s = 0; s < 8; ++s)
#pragma unroll
        for (int t4 = 0; t4 < 4; ++t4)
            acc[t4] = MFMA16(af[s],
                *(const short8*)&Bs[(t4 * 16 + c) * 264 + q * 8 + 32 * s], acc[t4]);
    int grl = rbase + wv * 16 + q * 4;
#pragma unroll
    for (int t4 = 0; t4 < 4; ++t4) {
        int col = t4 * 16 + c;
        float bvv = fob[b * 64 + col];
#pragma unroll
        for (int reg = 0; reg < 4; ++reg) {
            int gr = grl + reg;
            if (gr < TT)
                out[(size_t)b * TT * 64 + (size_t)gr * 64 + col] = acc[t4][reg] + bvv;
        }
    }
}

// ---------------------------------------------------------------------------
extern "C" void kernel_launch(void* const* d_in, const int* in_sizes, int n_in,
                              void* d_out, int out_size, void* d_ws, size_t ws_size,
                              hipStream_t stream)
{
    const float* f0    = (const float*)d_in[0];
    const float* f1    = (const float*)d_in[1];
    const float* fcW   = (const float*)d_in[2];
    const float* fcb   = (const float*)d_in[3];
    const float* gatW  = (const float*)d_in[4];
    const float* al    = (const float*)d_in[5];
    const float* ar    = (const float*)d_in[6];
    const float* semW  = (const float*)d_in[7];
    const float* semb  = (const float*)d_in[8];
    const float* semq  = (const float*)d_in[9];
    const float* foW   = (const float*)d_in[10];
    const float* fob   = (const float*)d_in[11];
    const int* type_idx = (const int*)d_in[12];
    const int* node_idx = (const int*)d_in[13];
    const int* edge_src = (const int*)d_in[14];
    const int* edge_dst = (const int*)d_in[15];
    const int* tgt_idx  = (const int*)d_in[16];
    float* out = (float*)d_out;

    char* ws = (char*)d_ws;
    size_t off = 0;
    auto alloc = [&](size_t bytes) -> void* {
        void* p = ws + off;
        off = (off + bytes + 255) & ~(size_t)255;
        return p;
    };
    // fixed allocations first
    u16*   tbf         = (u16*)alloc((size_t)NT * 64 * 2);
    u16*   metab4      = (u16*)alloc((size_t)4 * TT * 256 * 2);
    float* wsum4       = (float*)alloc(64);
    u16*   fcWb        = (u16*)alloc(32768 * 2);
    u16*   gatWb       = (u16*)alloc(65536 * 2);
    u16*   semWb       = (u16*)alloc(131072 * 2);
    u16*   foWb        = (u16*)alloc(32768 * 2);
    int*   deg4        = (int*)alloc((size_t)4 * NPG * 4);
    int*   tflag4      = (int*)alloc((size_t)4 * NPG * 4);
    int*   offsets4    = (int*)alloc((size_t)4 * (NPG + 1) * 4);
    int*   cursor4     = (int*)alloc((size_t)4 * NPG * 4);
    int*   perm4       = (int*)alloc((size_t)4 * EG * 4);
    int*   part4       = (int*)alloc((size_t)4 * NPB * 4);
    int*   pref4       = (int*)alloc((size_t)4 * NPB * 4);
    // graph-batched buffers: as many graphs per batch as workspace allows;
    // prefer larger batch, then the per-edge score buffer (elp).
    const size_t perg_base = (size_t)NPG * 256 * 2 + 2 * (size_t)NPG * 4 * 4 + 768;
    const size_t perg_elp  = perg_base + (size_t)EG * 16 + 256;
    int GPB = 1; bool use_elp = false;
    {
        size_t rem = (ws_size > off) ? ws_size - off : 0;
        if      (rem >= 4 * perg_elp)  { GPB = 4; use_elp = true;  }
        else if (rem >= 4 * perg_base) { GPB = 4; use_elp = false; }
        else if (rem >= 2 * perg_elp)  { GPB = 2; use_elp = true;  }
        else if (rem >= 2 * perg_base) { GPB = 2; use_elp = false; }
        else if (rem >= 1 * perg_elp)  { GPB = 1; use_elp = true;  }
    }
    u16*   zb          = (u16*)alloc((size_t)GPB * NPG * 256 * 2);
    float* el          = (float*)alloc((size_t)GPB * NPG * 4 * 4);
    float* er          = (float*)alloc((size_t)GPB * NPG * 4 * 4);
    float* elp         = use_elp ? (float*)alloc((size_t)GPB * EG * 16) : (float*)0;

    const int eblocks = (EG + 255) / 256;
    const int tblocks = (TT + 255) / 256;

    prep_kernel<<<512, 256, 0, stream>>>(fcW, gatW, semW, foW,
                                         fcWb, gatWb, semWb, foWb);

    // --- batched target-only CSR build for all 4 graphs ---
    hipMemsetAsync(deg4, 0, (size_t)4 * NPG * 4, stream);
    hipMemsetAsync(tflag4, 0, (size_t)4 * NPG * 4, stream);
    hipMemsetAsync(wsum4, 0, 16, stream);
    mark_kernel<<<dim3(tblocks, 4), 256, 0, stream>>>(tgt_idx, tflag4);
    count4_kernel<<<dim3(eblocks, 4), 256, 0, stream>>>(edge_dst, tflag4, deg4);
    partial4_kernel<<<dim3(NPB, 4), 256, 0, stream>>>(deg4, part4);
    scanp_kernel<<<dim3(1, 4), 256, 0, stream>>>(part4, pref4, offsets4);
    distribute_kernel<<<dim3(NPB, 4), 256, 0, stream>>>(deg4, pref4, offsets4,
                                                        cursor4);
    scatter4_kernel<<<dim3(eblocks, 4), 256, 0, stream>>>(edge_dst, edge_src,
                                                          tflag4, cursor4, perm4);

    fc_kernel<<<dim3(782, 2), 256, 0, stream>>>(f0, f1, fcWb, fcb, type_idx, tbf);
    for (int g0 = 0; g0 < 4; g0 += GPB) {
        z_kernel<<<dim3(782, GPB), 256, 0, stream>>>(
            tbf, node_idx, gatWb, al, ar, zb, el, er, g0);
        if (elp)
            escore_kernel<<<dim3(eblocks, GPB), 256, 0, stream>>>(
                perm4, offsets4, el, elp, g0);
        agg_kernel<<<dim3(TT / 4, GPB), 256, 0, stream>>>(
            tgt_idx, offsets4, perm4, elp, el, er, zb, metab4, g0);
    }
    sem_kernel<<<dim3(313, 4), 256, 0, stream>>>(metab4, semWb, semb, semq,
                                                 wsum4);
    out_kernel<<<dim3(313, 2), 256, 0, stream>>>(metab4, wsum4, foWb, fob, out);
}